// Round 3
// baseline (366.894 us; speedup 1.0000x reference)
//
#include <hip/hip_runtime.h>

// BinarizeLinear: out[65536,1024] = x @ sign(W)^T + bias
// Round 3: "B-direct" — prepass stores sign(W) as bf16 in MFMA-fragment order
// (WF[nb][kb][lane][8], 2 MB in d_ws); GEMM loads B fragments straight from
// L2 (coalesced 1KB/wave bursts), no LDS for B. A (x) is reg-staged with fused
// fp32->bf16 cvt into XOR-swizzled LDS (conflict-free ds_read_b128/ds_write).
// 128x128 tile, BK=64, 4 waves, double-buffered A (32 KB), XCD-bijective swizzle.

typedef __bf16 bf16x8 __attribute__((ext_vector_type(8)));
typedef __bf16 bf16x4 __attribute__((ext_vector_type(4)));
typedef float  f32x4  __attribute__((ext_vector_type(4)));

constexpr int Mdim = 65536;
constexpr int Ndim = 1024;
constexpr int Kdim = 1024;
constexpr int BM = 128, BN = 128, BK = 64;
constexpr int NKT = Kdim / BK;          // 16 K-tiles
constexpr int NB_N = Ndim / 16;         // 64 n-blocks
constexpr int NB_K = Kdim / 32;         // 32 k-blocks

// ---- prepass: W fp32 -> sign() bf16 in fragment order ----
// WF[(nb*32 + kb)*64 + lane][e] = sign(W[nb*16 + (lane&15)][kb*32 + (lane>>4)*8 + e])
__global__ __launch_bounds__(256)
void wfrag_kernel(const float* __restrict__ W, __bf16* __restrict__ WF) {
    const int lane = threadIdx.x & 63;
    const int wid  = threadIdx.x >> 6;
    const int id   = blockIdx.x * 4 + wid;        // 0..2047 subtiles
    const int nb   = id >> 5;
    const int kb   = id & 31;
    const float* src = W + (size_t)(nb * 16 + (lane & 15)) * Kdim
                         + kb * 32 + (lane >> 4) * 8;
    f32x4 a = *(const f32x4*)src;
    f32x4 b = *(const f32x4*)(src + 4);
    bf16x8 o;
#pragma unroll
    for (int e = 0; e < 4; ++e) {
        o[e]     = (__bf16)(float)((a[e] > 0.f) - (a[e] < 0.f));
        o[e + 4] = (__bf16)(float)((b[e] > 0.f) - (b[e] < 0.f));
    }
    *(bf16x8*)(WF + ((size_t)id * 64 + lane) * 8) = o;
}

// ---- main GEMM, B-direct ----
__global__ __launch_bounds__(256)
void binlin_bdirect(const float* __restrict__ X, const __bf16* __restrict__ WF,
                    const float* __restrict__ bias, float* __restrict__ out)
{
    __shared__ __align__(16) __bf16 Al[2][BM][BK];   // 2 x 16 KB, XOR-swizzled

    constexpr int NWG = (Mdim / BM) * (Ndim / BN);   // 4096
    const int swz  = (blockIdx.x & 7) * (NWG / 8) + (blockIdx.x >> 3);
    const int colb = swz & 7;
    const int rowb = swz >> 3;
    const int row0 = rowb * BM;
    const int col0 = colb * BN;

    const int tid  = threadIdx.x;
    const int lane = tid & 63;
    const int wid  = tid >> 6;
    const int wr   = wid >> 1;        // 2x2 waves -> 64x64 output sub-tile each
    const int wc   = wid & 1;

    // A staging: pass p (0..7): row = p*16 + (tid>>4), 16B chunk = (tid&15)
    // -> each wave inst reads 1 KB contiguous from x (perfect coalescing)
    const int srow = tid >> 4;        // 0..15 (row within pass slab)
    const int scol = (tid & 15) * 4;  // fp32 col

    const float* Xb = X + (size_t)(row0 + srow) * Kdim + scol;

    f32x4 ra[8];
    auto GLA = [&](int k0) {
#pragma unroll
        for (int p = 0; p < 8; ++p)
            ra[p] = *(const f32x4*)(Xb + (size_t)(p * 16) * Kdim + k0);
    };
    auto DSWA = [&](int buf) {
#pragma unroll
        for (int p = 0; p < 8; ++p) {
            bf16x4 v;
#pragma unroll
            for (int e = 0; e < 4; ++e) v[e] = (__bf16)ra[p][e];
            const int row = p * 16 + srow;
            const int byte = (scol * 2) ^ ((row & 7) << 4);   // XOR swizzle
            *(bf16x4*)((char*)&Al[buf][row][0] + byte) = v;
        }
    };

    f32x4 acc[4][4] = {};
    const int fr  = lane & 15;
    const int ksl = (lane >> 4) * 8;  // elem offset within a 32-k step
    const int nb0 = (col0 >> 4) + wc * 4;

    auto COMP = [&](int buf, int kt) {
#pragma unroll
        for (int s = 0; s < 2; ++s) {
            const int kb = kt * 2 + s;
            bf16x8 bfr[4];
#pragma unroll
            for (int j = 0; j < 4; ++j)
                bfr[j] = *(const bf16x8*)(WF + (((size_t)(nb0 + j) * 32 + kb) * 64 + lane) * 8);
            bf16x8 af[4];
#pragma unroll
            for (int i = 0; i < 4; ++i) {
                const int row  = wr * 64 + i * 16 + fr;
                const int byte = ((s * 32 + ksl) * 2) ^ ((fr & 7) << 4);
                af[i] = *(const bf16x8*)((const char*)&Al[buf][row][0] + byte);
            }
#pragma unroll
            for (int i = 0; i < 4; ++i)
#pragma unroll
                for (int j = 0; j < 4; ++j)
                    acc[i][j] = __builtin_amdgcn_mfma_f32_16x16x32_bf16(
                        af[i], bfr[j], acc[i][j], 0, 0, 0);
        }
    };

    // prologue
    GLA(0);
    DSWA(0);
    __syncthreads();

    int cur = 0;
    for (int kt = 0; kt < NKT; ++kt) {
        if (kt + 1 < NKT) GLA((kt + 1) * BK);   // in flight during COMP
        COMP(cur, kt);
        if (kt + 1 < NKT) {
            DSWA(cur ^ 1);                       // waits A loads here (late use)
            __syncthreads();
            cur ^= 1;
        }
    }

    // epilogue: C[row = i*16 + (lane>>4)*4 + r][col = j*16 + (lane&15)]
    const int orow = row0 + wr * 64 + (lane >> 4) * 4;
    const int ocol = col0 + wc * 64 + fr;
#pragma unroll
    for (int j = 0; j < 4; ++j) {
        const float bv = bias[ocol + j * 16];
#pragma unroll
        for (int i = 0; i < 4; ++i) {
#pragma unroll
            for (int r = 0; r < 4; ++r) {
                out[(size_t)(orow + i * 16 + r) * Ndim + (ocol + j * 16)] =
                    acc[i][j][r] + bv;
            }
        }
    }
}

// ---- fallback (ws too small): round-2 reg-staged kernel, inline sign ----
__global__ __launch_bounds__(256)
void binlin_fallback(const float* __restrict__ X, const float* __restrict__ Wf,
                     const float* __restrict__ bias, float* __restrict__ out)
{
    __shared__ __align__(16) __bf16 Al[2][BM][32];
    __shared__ __align__(16) __bf16 Bl[2][BN][32];
    constexpr int NT = Kdim / 32;
    constexpr int NWG = (Mdim / BM) * (Ndim / BN);
    const int swz  = (blockIdx.x & 7) * (NWG / 8) + (blockIdx.x >> 3);
    const int colb = swz & 7, rowb = swz >> 3;
    const int row0 = rowb * BM, col0 = colb * BN;
    const int tid = threadIdx.x, lane = tid & 63, wid = tid >> 6;
    const int wr = wid >> 1, wc = wid & 1;
    const int sr = tid >> 2, sc = (tid & 3) * 8;
    const float* Xb = X + (size_t)row0 * Kdim;
    const float* Wb = Wf + (size_t)col0 * Kdim;
    f32x4 ra[2][2], rb[2][2];
    auto GL = [&](int k0) {
#pragma unroll
        for (int p = 0; p < 2; ++p) {
            const float* sa = Xb + (size_t)(p * 64 + sr) * Kdim + k0 + sc;
            ra[p][0] = *(const f32x4*)sa; ra[p][1] = *(const f32x4*)(sa + 4);
            const float* sb = Wb + (size_t)(p * 64 + sr) * Kdim + k0 + sc;
            rb[p][0] = *(const f32x4*)sb; rb[p][1] = *(const f32x4*)(sb + 4);
        }
    };
    auto DSW = [&](int buf) {
#pragma unroll
        for (int p = 0; p < 2; ++p) {
            bf16x8 va, vb;
#pragma unroll
            for (int e = 0; e < 4; ++e) {
                va[e] = (__bf16)ra[p][0][e]; va[e + 4] = (__bf16)ra[p][1][e];
                float a = rb[p][0][e], b = rb[p][1][e];
                vb[e] = (__bf16)(float)((a > 0.f) - (a < 0.f));
                vb[e + 4] = (__bf16)(float)((b > 0.f) - (b < 0.f));
            }
            *(bf16x8*)&Al[buf][p * 64 + sr][sc] = va;
            *(bf16x8*)&Bl[buf][p * 64 + sr][sc] = vb;
        }
    };
    f32x4 acc[4][4] = {};
    const int fr = lane & 15, ks = (lane >> 4) * 8;
    auto COMP = [&](int buf) {
        bf16x8 af[4], bf[4];
#pragma unroll
        for (int i = 0; i < 4; ++i) af[i] = *(const bf16x8*)&Al[buf][wr * 64 + fr + i * 16][ks];
#pragma unroll
        for (int j = 0; j < 4; ++j) bf[j] = *(const bf16x8*)&Bl[buf][wc * 64 + fr + j * 16][ks];
#pragma unroll
        for (int i = 0; i < 4; ++i)
#pragma unroll
            for (int j = 0; j < 4; ++j)
                acc[i][j] = __builtin_amdgcn_mfma_f32_16x16x32_bf16(af[i], bf[j], acc[i][j], 0, 0, 0);
    };
    GL(0); DSW(0); __syncthreads();
    int cur = 0;
    for (int t = 0; t < NT; ++t) {
        if (t + 1 < NT) GL((t + 1) * 32);
        COMP(cur);
        if (t + 1 < NT) { DSW(cur ^ 1); __syncthreads(); cur ^= 1; }
    }
    const int orow = row0 + wr * 64 + (lane >> 4) * 4;
    const int ocol = col0 + wc * 64 + fr;
#pragma unroll
    for (int j = 0; j < 4; ++j) {
        const float bv = bias[ocol + j * 16];
#pragma unroll
        for (int i = 0; i < 4; ++i)
#pragma unroll
            for (int r = 0; r < 4; ++r)
                out[(size_t)(orow + i * 16 + r) * Ndim + (ocol + j * 16)] = acc[i][j][r] + bv;
    }
}

extern "C" void kernel_launch(void* const* d_in, const int* in_sizes, int n_in,
                              void* d_out, int out_size, void* d_ws, size_t ws_size,
                              hipStream_t stream) {
    const float* x  = (const float*)d_in[0];
    const float* w  = (const float*)d_in[1];
    const float* b  = (const float*)d_in[2];
    float* out      = (float*)d_out;

    constexpr size_t WF_BYTES = (size_t)Ndim * Kdim * sizeof(__bf16);  // 2 MB
    dim3 grid((Mdim / BM) * (Ndim / BN));   // 4096 blocks

    if (ws_size >= WF_BYTES) {
        __bf16* wf = (__bf16*)d_ws;
        wfrag_kernel<<<dim3(512), dim3(256), 0, stream>>>(w, wf);
        binlin_bdirect<<<grid, dim3(256), 0, stream>>>(x, wf, b, out);
    } else {
        binlin_fallback<<<grid, dim3(256), 0, stream>>>(x, w, b, out);
    }
}

// Round 4
// 239.145 us; speedup vs baseline: 1.5342x; 1.5342x over previous
//
#include <hip/hip_runtime.h>

// BinarizeLinear: out[65536,1024] = x @ sign(W)^T + bias
// Round 4: 256x256 tile, BK=64, 8 waves (2M x 4N), guide's T-stack:
//   T1 XCD-bijective swizzle, T2 XOR LDS swizzle (both operands; B's swizzle
//   pre-baked into the d_ws image so global_load_lds stays linear, rule 21),
//   T3/T4 early-issue staging with single per-tile barrier (counted-wait by
//   construction: all in-flight vmem is ~4 phases old at the drain),
//   T5 setprio around each 16-MFMA quadrant.
// A (x fp32) reg-staged with fused fp32->bf16 cvt; B sign(W) bf16 prepassed
// into d_ws (2 MB) as per-(colb,kt) 32KB LDS images, staged via gload_lds.

typedef __bf16 bf16x8 __attribute__((ext_vector_type(8)));
typedef __bf16 bf16x4 __attribute__((ext_vector_type(4)));
typedef float  f32x4  __attribute__((ext_vector_type(4)));

constexpr int Mdim = 65536, Ndim = 1024, Kdim = 1024;
constexpr int BM = 256, BN = 256, BK = 64;
constexpr int NKT = Kdim / BK;        // 16 K-tiles
constexpr int NWG = (Mdim / BM) * (Ndim / BN);   // 1024 blocks

typedef const __attribute__((address_space(1))) char ga_char;
typedef __attribute__((address_space(3))) char lds_char;
__device__ __forceinline__ void gload16(const void* g, void* l) {
    __builtin_amdgcn_global_load_lds((ga_char*)g, (lds_char*)l, 16, 0, 0);
}
__device__ __forceinline__ f32x4 mfma16(bf16x8 a, bf16x8 b, f32x4 c) {
    return __builtin_amdgcn_mfma_f32_16x16x32_bf16(a, b, c, 0, 0, 0);
}

// ---- prepass: WS[(colb*16+kt)*16384 + row*64 + (c ^ (row&7))*8 ..+8] =
//      sign(W[colb*256+row][kt*64 + c*8 ..+8]) as bf16  (32KB LDS image/block)
__global__ __launch_bounds__(256)
void wprep_kernel(const float* __restrict__ W, __bf16* __restrict__ WS) {
    const int id = blockIdx.x * 256 + threadIdx.x;   // 131072 = 1024*16*8
    const int c  = id & 7;
    const int kt = (id >> 3) & 15;
    const int n  = id >> 7;                          // 0..1023 (W row)
    const float* src = W + (size_t)n * Kdim + kt * 64 + c * 8;
    f32x4 a = *(const f32x4*)src;
    f32x4 b = *(const f32x4*)(src + 4);
    bf16x8 o;
#pragma unroll
    for (int e = 0; e < 4; ++e) {
        o[e]     = (__bf16)(float)((a[e] > 0.f) - (a[e] < 0.f));
        o[e + 4] = (__bf16)(float)((b[e] > 0.f) - (b[e] < 0.f));
    }
    const int row  = n & 255;
    const int colb = n >> 8;
    __bf16* dst = WS + (size_t)(colb * 16 + kt) * 16384
                + row * 64 + ((c ^ (row & 7)) * 8);
    *(bf16x8*)dst = o;
}

// ---- main GEMM ----
__global__ __launch_bounds__(512, 2)
void binlin256(const float* __restrict__ X, const __bf16* __restrict__ WS,
               const float* __restrict__ bias, float* __restrict__ out)
{
    __shared__ __align__(16) __bf16 Al[2][BM * BK];   // 2 x 32 KB, XOR-swizzled
    __shared__ __align__(16) __bf16 Bl[2][BN * BK];   // 2 x 32 KB, XOR-swizzled

    // T1: bijective chunked XCD swizzle (1024 % 8 == 0), col-fastest
    const int swz  = (blockIdx.x & 7) * (NWG / 8) + (blockIdx.x >> 3);
    const int colb = swz & 3;
    const int rowb = swz >> 2;
    const int row0 = rowb * BM;

    const int tid  = threadIdx.x;
    const int lane = tid & 63;
    const int wid  = tid >> 6;         // 0..7
    const int wr   = wid >> 2;         // M half (128 rows)
    const int wcn  = wid & 3;          // N quarter (64 cols)
    const int fr   = lane & 15;
    const int hq   = lane >> 4;        // 0..3

    // A staging map: pass q=0..7: row = q*32 + (tid>>4), 16B-fp32 chunk = tid&15
    const int s_r = tid >> 4;          // 0..31
    const int s_c = tid & 15;          // 0..15
    const float* Xb = X + (size_t)(row0 + s_r) * Kdim + s_c * 4;

    const __bf16* WSb = WS + (size_t)colb * 16 * 16384;

    f32x4 ra[8];
    auto GLA = [&](int kt) {
        const float* p = Xb + kt * 64;
#pragma unroll
        for (int q = 0; q < 8; ++q)
            ra[q] = *(const f32x4*)(p + (size_t)(q * 32) * Kdim);
    };
    auto DSWA = [&](int buf) {        // fused cvt + swizzled ds_write_b64
#pragma unroll
        for (int q = 0; q < 8; ++q) {
            bf16x4 v;
#pragma unroll
            for (int e = 0; e < 4; ++e) v[e] = (__bf16)ra[q][e];
            const int row  = q * 32 + s_r;
            const int byte = row * 128 + (((s_c >> 1) ^ (row & 7)) << 4)
                           + (s_c & 1) * 8;
            *(bf16x4*)((char*)&Al[buf][0] + byte) = v;
        }
    };
    auto STB = [&](int buf, int kt) { // 4 x gload16 per wave = 4 KB
        const __bf16* s0 = WSb + (size_t)kt * 16384 + wid * 2048 + lane * 8;
#pragma unroll
        for (int i = 0; i < 4; ++i)
            gload16(s0 + i * 512, &Bl[buf][wid * 2048 + i * 512]);
    };

    auto lda = [&](int buf, int i, int ks) -> bf16x8 {
        const int row  = wr * 128 + i * 16 + fr;
        const int byte = row * 128 + (((ks * 4 + hq) ^ (row & 7)) << 4);
        return *(const bf16x8*)((const char*)&Al[buf][0] + byte);
    };
    auto ldb = [&](int buf, int j, int ks) -> bf16x8 {
        const int row  = wcn * 64 + j * 16 + fr;
        const int byte = row * 128 + (((ks * 4 + hq) ^ (row & 7)) << 4);
        return *(const bf16x8*)((const char*)&Bl[buf][0] + byte);
    };

    f32x4 acc[8][4] = {};

    // prologue: stage tile 0
    GLA(0);
    STB(0, 0);
    DSWA(0);
    __syncthreads();

    int cur = 0;
    for (int kt = 0; kt < NKT; ++kt) {
        const int nxt = cur ^ 1;
        const bool pre = (kt + 1 < NKT);
        if (pre) { GLA(kt + 1); STB(nxt, kt + 1); }   // issue early (T14/T3)

        bf16x8 a0[4], a1[4], b0[4], b1[4];

        // phase 0: quadrant (m 0-3, ks0)
#pragma unroll
        for (int j = 0; j < 4; ++j) b0[j] = ldb(cur, j, 0);
#pragma unroll
        for (int i = 0; i < 4; ++i) a0[i] = lda(cur, i, 0);
        __builtin_amdgcn_s_setprio(1);
#pragma unroll
        for (int i = 0; i < 4; ++i)
#pragma unroll
            for (int j = 0; j < 4; ++j)
                acc[i][j] = mfma16(a0[i], b0[j], acc[i][j]);
        __builtin_amdgcn_s_setprio(0);

        // phase 1: quadrant (m 4-7, ks0)
#pragma unroll
        for (int i = 0; i < 4; ++i) a1[i] = lda(cur, i + 4, 0);
        __builtin_amdgcn_s_setprio(1);
#pragma unroll
        for (int i = 0; i < 4; ++i)
#pragma unroll
            for (int j = 0; j < 4; ++j)
                acc[i + 4][j] = mfma16(a1[i], b0[j], acc[i + 4][j]);
        __builtin_amdgcn_s_setprio(0);

        // phase 2: quadrant (m 0-3, ks1)
#pragma unroll
        for (int j = 0; j < 4; ++j) b1[j] = ldb(cur, j, 1);
#pragma unroll
        for (int i = 0; i < 4; ++i) a0[i] = lda(cur, i, 1);
        __builtin_amdgcn_s_setprio(1);
#pragma unroll
        for (int i = 0; i < 4; ++i)
#pragma unroll
            for (int j = 0; j < 4; ++j)
                acc[i][j] = mfma16(a0[i], b1[j], acc[i][j]);
        __builtin_amdgcn_s_setprio(0);

        // phase 3: quadrant (m 4-7, ks1) + late A write (cvt waits its loads)
#pragma unroll
        for (int i = 0; i < 4; ++i) a1[i] = lda(cur, i + 4, 1);
        if (pre) DSWA(nxt);
        __builtin_amdgcn_s_setprio(1);
#pragma unroll
        for (int i = 0; i < 4; ++i)
#pragma unroll
            for (int j = 0; j < 4; ++j)
                acc[i + 4][j] = mfma16(a1[i], b1[j], acc[i + 4][j]);
        __builtin_amdgcn_s_setprio(0);

        __syncthreads();   // single per-tile drain; in-flight vmem is old
        cur = nxt;
    }

    // epilogue: C frag (i,j): row = i*16 + hq*4 + r, col = j*16 + fr
    const int orow = row0 + wr * 128 + hq * 4;
    const int ocol = colb * 256 + wcn * 64 + fr;
#pragma unroll
    for (int j = 0; j < 4; ++j) {
        const float bv = bias[ocol + j * 16];
#pragma unroll
        for (int i = 0; i < 8; ++i)
#pragma unroll
            for (int r = 0; r < 4; ++r)
                out[(size_t)(orow + i * 16 + r) * Ndim + (ocol + j * 16)] =
                    acc[i][j][r] + bv;
    }
}

// ---- fallback (ws too small): reg-staged 128x128, inline sign ----
__global__ __launch_bounds__(256)
void binlin_fallback(const float* __restrict__ X, const float* __restrict__ Wf,
                     const float* __restrict__ bias, float* __restrict__ out)
{
    __shared__ __align__(16) __bf16 Al[2][128][32];
    __shared__ __align__(16) __bf16 Bl[2][128][32];
    constexpr int NT = Kdim / 32;
    const int swz  = (blockIdx.x & 7) * (4096 / 8) + (blockIdx.x >> 3);
    const int colb = swz & 7, rowb = swz >> 3;
    const int row0 = rowb * 128, col0 = colb * 128;
    const int tid = threadIdx.x, lane = tid & 63, wid = tid >> 6;
    const int wr = wid >> 1, wc = wid & 1;
    const int sr = tid >> 2, sc = (tid & 3) * 8;
    const float* Xb = X + (size_t)row0 * Kdim;
    const float* Wb = Wf + (size_t)col0 * Kdim;
    f32x4 ra[2][2], rb[2][2];
    auto GL = [&](int k0) {
#pragma unroll
        for (int p = 0; p < 2; ++p) {
            const float* sa = Xb + (size_t)(p * 64 + sr) * Kdim + k0 + sc;
            ra[p][0] = *(const f32x4*)sa; ra[p][1] = *(const f32x4*)(sa + 4);
            const float* sb = Wb + (size_t)(p * 64 + sr) * Kdim + k0 + sc;
            rb[p][0] = *(const f32x4*)sb; rb[p][1] = *(const f32x4*)(sb + 4);
        }
    };
    auto DSW = [&](int buf) {
#pragma unroll
        for (int p = 0; p < 2; ++p) {
            bf16x8 va, vb;
#pragma unroll
            for (int e = 0; e < 4; ++e) {
                va[e] = (__bf16)ra[p][0][e]; va[e + 4] = (__bf16)ra[p][1][e];
                float a = rb[p][0][e], b = rb[p][1][e];
                vb[e] = (__bf16)(float)((a > 0.f) - (a < 0.f));
                vb[e + 4] = (__bf16)(float)((b > 0.f) - (b < 0.f));
            }
            *(bf16x8*)&Al[buf][p * 64 + sr][sc] = va;
            *(bf16x8*)&Bl[buf][p * 64 + sr][sc] = vb;
        }
    };
    f32x4 acc[4][4] = {};
    const int fr = lane & 15, ks = (lane >> 4) * 8;
    auto COMP = [&](int buf) {
        bf16x8 af[4], bf[4];
#pragma unroll
        for (int i = 0; i < 4; ++i) af[i] = *(const bf16x8*)&Al[buf][wr * 64 + fr + i * 16][ks];
#pragma unroll
        for (int j = 0; j < 4; ++j) bf[j] = *(const bf16x8*)&Bl[buf][wc * 64 + fr + j * 16][ks];
#pragma unroll
        for (int i = 0; i < 4; ++i)
#pragma unroll
            for (int j = 0; j < 4; ++j)
                acc[i][j] = mfma16(af[i], bf[j], acc[i][j]);
    };
    GL(0); DSW(0); __syncthreads();
    int cur = 0;
    for (int t = 0; t < NT; ++t) {
        if (t + 1 < NT) GL((t + 1) * 32);
        COMP(cur);
        if (t + 1 < NT) { DSW(cur ^ 1); __syncthreads(); cur ^= 1; }
    }
    const int orow = row0 + wr * 64 + (lane >> 4) * 4;
    const int ocol = col0 + wc * 64 + fr;
#pragma unroll
    for (int j = 0; j < 4; ++j) {
        const float bv = bias[ocol + j * 16];
#pragma unroll
        for (int i = 0; i < 4; ++i)
#pragma unroll
            for (int r = 0; r < 4; ++r)
                out[(size_t)(orow + i * 16 + r) * Ndim + (ocol + j * 16)] = acc[i][j][r] + bv;
    }
}

extern "C" void kernel_launch(void* const* d_in, const int* in_sizes, int n_in,
                              void* d_out, int out_size, void* d_ws, size_t ws_size,
                              hipStream_t stream) {
    const float* x  = (const float*)d_in[0];
    const float* w  = (const float*)d_in[1];
    const float* b  = (const float*)d_in[2];
    float* out      = (float*)d_out;

    constexpr size_t WS_BYTES = (size_t)Ndim * Kdim * sizeof(__bf16);  // 2 MB

    if (ws_size >= WS_BYTES) {
        __bf16* ws = (__bf16*)d_ws;
        wprep_kernel<<<dim3(512), dim3(256), 0, stream>>>(w, ws);
        binlin256<<<dim3(NWG), dim3(512), 0, stream>>>(x, ws, b, out);
    } else {
        binlin_fallback<<<dim3(4096), dim3(256), 0, stream>>>(x, w, b, out);
    }
}